// Round 4
// baseline (7046.519 us; speedup 1.0000x reference)
//
#include <hip/hip_runtime.h>
#include <stdint.h>

typedef unsigned long long u64;

#define VOCAB 128
#define RD 128
#define DM 1024
#define NFF 6
#define BATCH 64
#define TSTEPS 512

// ---------------------------------------------------------------------------
// ws layout:
//   [0, 786432)          ffbits  [i][w][j] u64   (i<6, w<16, j<1024)
//   [786432, +2048)      ebits   [v][2]    u64   (v<128)
//   [788480, +2048)      headb   [v][2]    u64   (v<128)
//   [790528, +512)       losses  [64]      double
// ---------------------------------------------------------------------------

// Pack ff sign bits: bit b of word (i,w,j) = (ff[i][w*64+b][j] < 0)  (1 => -1)
__global__ void pack_ff(const float* __restrict__ ff, u64* __restrict__ ffb) {
    int wid  = blockIdx.x * (blockDim.x >> 6) + (threadIdx.x >> 6); // wave id, 0..1535
    int lane = threadIdx.x & 63;
    int jt = wid & 15;
    int w  = (wid >> 4) & 15;
    int i  = wid >> 8;
    int j  = jt * 64 + lane;
    const float* src = ff + ((size_t)(i * DM) + w * 64) * DM + j;
    u64 word = 0;
#pragma unroll
    for (int b = 0; b < 64; ++b) {
        float v = src[(size_t)b * DM];
        word |= (u64)(v < 0.0f) << b;
    }
    ffb[((i * 16 + w) << 10) + j] = word;
}

// Pack embed rows and head columns (tiny).
__global__ void pack_small(const float* __restrict__ emb, const float* __restrict__ head,
                           u64* __restrict__ eb, u64* __restrict__ hb) {
    int tid = threadIdx.x; // 0..255
    if (tid < 128) {
        int v = tid;
        for (int wd = 0; wd < 2; ++wd) {
            u64 word = 0;
            for (int l = 0; l < 64; ++l)
                word |= (u64)(emb[v * RD + wd * 64 + l] < 0.0f) << l;
            eb[v * 2 + wd] = word;
        }
    } else {
        int v = tid - 128;
        for (int wd = 0; wd < 2; ++wd) {
            u64 word = 0;
            for (int l = 0; l < 64; ++l)
                word |= (u64)(head[(wd * 64 + l) * VOCAB + v] < 0.0f) << l;
            hb[v * 2 + wd] = word;
        }
    }
}

// Main recurrent kernel: one block per batch row, thread j owns column j.
// All 6 layers' packed weight columns (96 u64) are pinned into the AGPR
// class ("+a" empty asm): AGPRs are a separate 256-slot budget per wave, so
// VGPR-class pressure stays low and the allocator has no reason to spill.
// CDNA2+ VALU reads AGPR operands directly (or via 1-cy v_accvgpr_read).
__global__ void __launch_bounds__(1024, 4)
brnn_main(const int* __restrict__ tokens,
          const float* __restrict__ initial_lat,
          const float* __restrict__ thr_lat,
          const u64* __restrict__ ffb,
          const u64* __restrict__ eb,
          const u64* __restrict__ hb,
          double* __restrict__ losses) {
    const int b    = blockIdx.x;
    const int tid  = threadIdx.x;
    const int lane = tid & 63;
    const int wv   = tid >> 6;

    __shared__ __align__(16) u64 hbuf[2][16];

    // --- load packed ff columns into AGPR-resident registers ---
    u64 fr[NFF][16];
#pragma unroll
    for (int i = 0; i < NFF; ++i)
#pragma unroll
        for (int w = 0; w < 16; ++w) {
            u64 v = ffb[((i * 16 + w) << 10) + tid];
            asm volatile("" : "+a"(v));   // pin in AGPR class: no remat, no VGPR pressure
            fr[i][w] = v;
        }

    // thresholds -> popcount cutoffs:  bit(-1) <=> pre < thr  <=>  acc >= cthr
    int cthr[NFF];
#pragma unroll
    for (int i = 0; i < NFF; ++i) {
        int thr = (int)rintf(thr_lat[i * DM + tid]); // round-half-even == jnp.round
        cthr[i] = ((DM - thr) >> 1) + 1;
    }

    // head bits (used by wave 0 only; loaded uniformly, pinned in AGPRs)
    u64 h0a = hb[lane * 2 + 0];
    u64 h0b = hb[lane * 2 + 1];
    u64 h1a = hb[(lane + 64) * 2 + 0];
    u64 h1b = hb[(lane + 64) * 2 + 1];
    asm volatile("" : "+a"(h0a), "+a"(h0b), "+a"(h1a), "+a"(h1b));

    // --- init h = sign(initial_lat), into buffer 0 ---
    {
        u64 m = __ballot(initial_lat[tid] < 0.0f);
        if (lane == 0) hbuf[0][wv] = m;
    }
    __syncthreads();

    const int* toks = tokens + b * TSTEPS;
    double lacc = 0.0;
    int p = 0; // current h buffer (always 0 at step boundaries: 6 flips/step)

    for (int t = 0; t < TSTEPS; ++t) {
        int tok = toks[t]; // uniform -> scalar load

        // prefetch embed bits for the end-of-step splice (hides under 6 layers)
        u64 enew = 0;
        if (wv == 0 && lane < 2) enew = eb[tok * 2 + lane];

        // --- 6 binary FF layers ---
#pragma unroll
        for (int i = 0; i < NFF; ++i) {
            const ulonglong2* hp = (const ulonglong2*)hbuf[p];
            int acc = 0;
#pragma unroll
            for (int q = 0; q < 8; ++q) {
                ulonglong2 hv = hp[q]; // broadcast ds_read_b128 (conflict-free)
                acc += __popcll(hv.x ^ fr[i][2 * q]) + __popcll(hv.y ^ fr[i][2 * q + 1]);
            }
            u64 m = __ballot(acc >= cthr[i]);
            if (lane == 0) hbuf[p ^ 1][wv] = m;
            p ^= 1;
            __syncthreads();
        }

        // --- head + log-softmax + loss + embed splice (wave 0 only) ---
        if (wv == 0) {
            u64 r0 = hbuf[p][14], r1 = hbuf[p][15];
            int d0 = 128 - 2 * (__popcll(r0 ^ h0a) + __popcll(r1 ^ h0b));
            int d1 = 128 - 2 * (__popcll(r0 ^ h1a) + __popcll(r1 ^ h1b));
            float l0 = (float)d0 * (1.0f / 16.0f);
            float l1 = (float)d1 * (1.0f / 16.0f);
            float mx = fmaxf(l0, l1);
#pragma unroll
            for (int s = 32; s >= 1; s >>= 1) mx = fmaxf(mx, __shfl_xor(mx, s));
            float se = __expf(l0 - mx) + __expf(l1 - mx);
#pragma unroll
            for (int s = 32; s >= 1; s >>= 1) se += __shfl_xor(se, s);
            int   tl   = tok & 63;
            float la   = __shfl(l0, tl);
            float lb   = __shfl(l1, tl);
            float ltok = (tok >> 6) ? lb : la;
            lacc += (double)(mx + __logf(se) - ltok);
            // splice x_new read-part = sign(embed[tok]) into words 14,15
            if (lane < 2) hbuf[p][14 + lane] = enew;
        }
        __syncthreads();
    }

    if (tid == 0) losses[b] = lacc;
}

__global__ void reduce_loss(const double* __restrict__ losses, float* __restrict__ out) {
    int lane = threadIdx.x; // 64 threads, 1 wave
    double v = losses[lane];
#pragma unroll
    for (int s = 32; s >= 1; s >>= 1) v += __shfl_down(v, s);
    if (lane == 0) out[0] = (float)(v * (1.0 / ((double)BATCH * (double)TSTEPS)));
}

extern "C" void kernel_launch(void* const* d_in, const int* in_sizes, int n_in,
                              void* d_out, int out_size, void* d_ws, size_t ws_size,
                              hipStream_t stream) {
    const int*   tokens  = (const int*)d_in[0];   // (64, 512) int32
    const float* initial = (const float*)d_in[1]; // (1024,)
    const float* embed   = (const float*)d_in[2]; // (128, 128)
    const float* ff      = (const float*)d_in[3]; // (6, 1024, 1024)
    const float* head    = (const float*)d_in[4]; // (128, 128)
    const float* thrl    = (const float*)d_in[5]; // (6, 1024)

    char* ws = (char*)d_ws;
    u64*    ffb    = (u64*)ws;                      // 786432 B
    u64*    eb     = (u64*)(ws + 786432);           // 2048 B
    u64*    hb     = (u64*)(ws + 786432 + 2048);    // 2048 B
    double* losses = (double*)(ws + 786432 + 4096); // 512 B

    pack_ff<<<384, 256, 0, stream>>>(ff, ffb);
    pack_small<<<1, 256, 0, stream>>>(embed, head, eb, hb);
    brnn_main<<<BATCH, 1024, 0, stream>>>(tokens, initial, thrl, ffb, eb, hb, losses);
    reduce_loss<<<1, 64, 0, stream>>>(losses, (float*)d_out);
}